// Round 13
// baseline (2495.199 us; speedup 1.0000x reference)
//
#include <hip/hip_runtime.h>

#define BATCH 524288
#define NOISE_STD 0.4466835921509630f
#define INV_SQRT2 0.7071067811865476f

__device__ __forceinline__ float eluf(float x) {
    return x > 0.0f ? x : __expf(x) - 1.0f;
}

// tanh(x) = 1 - 2/(exp(2x)+1); exp->inf gives 1, exp->0 gives -1 (no clamp needed)
__device__ __forceinline__ float ftanh(float x) {
    float t = __expf(2.0f * x);
    return 1.0f - __fdividef(2.0f, t + 1.0f);
}

// enc LDS weight layout (floats). All matrix bases and rows 16B-aligned so
// compile-time-indexed reads merge into ds_read_b128 (zero VALU per weight).
#define W1_   0
#define B1_   256
#define W2_   272
#define B2_   528
#define CW1_  544
#define CB1_  560
#define CW2_  568
#define CB2_  824
#define CW3_  832
#define CB3_  960
#define CW4_  968
#define CB4_  1096
#define W3_   1104
#define B3_   2128
#define W4_   2160
#define B4_   2672
#define NWL   2688

// R11: 27k VALU inst/thread vs 6.5k ideal = per-use weight-load overhead.
// Weights now staged in LDS -> broadcast ds_read w/ immediate offsets.
__global__ __attribute__((amdgpu_flat_work_group_size(256,256), amdgpu_waves_per_eu(2,4)))
void enc_kernel(
    const float* __restrict__ x,
    const float* __restrict__ w1, const float* __restrict__ b1,
    const float* __restrict__ w2, const float* __restrict__ b2,
    const float* __restrict__ cw1, const float* __restrict__ cb1,
    const float* __restrict__ cw2, const float* __restrict__ cb2,
    const float* __restrict__ cw3, const float* __restrict__ cb3,
    const float* __restrict__ cw4, const float* __restrict__ cb4,
    const float* __restrict__ w3, const float* __restrict__ b3,
    const float* __restrict__ w4, const float* __restrict__ b4,
    float* __restrict__ g_out, float* __restrict__ partials)
{
    __shared__ __align__(16) float wl[NWL];
    __shared__ float h2s[256][17];   // odd stride: conflict-free row access

    const int tid = threadIdx.x;
    const int row = blockIdx.x * 256 + tid;

    // ---- cooperative weight staging (one-time per block) ----
    wl[W1_  + tid] = w1[tid];
    wl[W2_  + tid] = w2[tid];
    wl[CW2_ + tid] = cw2[tid];
    wl[W3_        + tid] = w3[tid];
    wl[W3_ + 256  + tid] = w3[256 + tid];
    wl[W3_ + 512  + tid] = w3[512 + tid];
    wl[W3_ + 768  + tid] = w3[768 + tid];
    wl[W4_        + tid] = w4[tid];
    wl[W4_ + 256  + tid] = w4[256 + tid];
    if (tid < 128) { wl[CW3_ + tid] = cw3[tid]; wl[CW4_ + tid] = cw4[tid]; }
    if (tid < 32)  { wl[B3_ + tid] = b3[tid]; }
    if (tid < 16)  { wl[B1_ + tid] = b1[tid]; wl[B2_ + tid] = b2[tid];
                     wl[B4_ + tid] = b4[tid]; wl[CW1_ + tid] = cw1[tid]; }
    if (tid < 8)   { wl[CB1_ + tid] = cb1[tid]; wl[CB2_ + tid] = cb2[tid];
                     wl[CB3_ + tid] = cb3[tid]; wl[CB4_ + tid] = cb4[tid]; }

    float v[16];
    {
        const float4* xp = (const float4*)(x + (size_t)row * 16);
        float4 a0 = xp[0], a1 = xp[1], a2 = xp[2], a3 = xp[3];
        v[0]=a0.x; v[1]=a0.y; v[2]=a0.z; v[3]=a0.w;
        v[4]=a1.x; v[5]=a1.y; v[6]=a1.z; v[7]=a1.w;
        v[8]=a2.x; v[9]=a2.y; v[10]=a2.z; v[11]=a2.w;
        v[12]=a3.x; v[13]=a3.y; v[14]=a3.z; v[15]=a3.w;
    }

    __syncthreads();   // weights visible

    // dense1 + ELU
    float h1[16];
#pragma unroll
    for (int j = 0; j < 16; ++j) h1[j] = wl[B1_ + j];
#pragma unroll
    for (int i = 0; i < 16; ++i) {
        float vi = v[i];
#pragma unroll
        for (int j = 0; j < 16; ++j) h1[j] += vi * wl[W1_ + i*16 + j];
    }
#pragma unroll
    for (int j = 0; j < 16; ++j) h1[j] = eluf(h1[j]);

    // dense2 + ELU -> h2 (regs) + LDS copy for runtime indexing in the conv loop
    float h2[16];
#pragma unroll
    for (int j = 0; j < 16; ++j) h2[j] = wl[B2_ + j];
#pragma unroll
    for (int i = 0; i < 16; ++i) {
        float vi = h1[i];
#pragma unroll
        for (int j = 0; j < 16; ++j) h2[j] += vi * wl[W2_ + i*16 + j];
    }
#pragma unroll
    for (int j = 0; j < 16; ++j) {
        h2[j] = eluf(h2[j]);
        h2s[tid][j] = h2[j];
    }

    // ---- conv pipeline: 3 rolled iterations, 2 conv2 positions each ----
    float cA[8], cB[8];          // carry: c1[4pp], c1[4pp+1]
#pragma unroll
    for (int ic = 0; ic < 8; ++ic) {
        cA[ic] = ftanh(wl[CB1_+ic] + wl[CW1_+ic*2]*h2[0] + wl[CW1_+ic*2+1]*h2[1]);
        cB[ic] = ftanh(wl[CB1_+ic] + wl[CW1_+ic*2]*h2[1] + wl[CW1_+ic*2+1]*h2[2]);
    }
    float o2p[8], o3p[8];        // o2[2pp-1], o3[2pp-2] carries
#pragma unroll
    for (int ic = 0; ic < 8; ++ic) { o2p[ic] = 0.0f; o3p[ic] = 0.0f; }

    float t3[32];
#pragma unroll
    for (int j = 0; j < 32; ++j) t3[j] = wl[B3_ + j];

#pragma unroll 1
    for (int pp = 0; pp < 3; ++pp) {
        const float* hrow = &h2s[tid][0];
        const int b4i = 4*pp;
        float e2 = hrow[b4i+2], e3 = hrow[b4i+3], e4 = hrow[b4i+4],
              e5 = hrow[b4i+5], e6 = hrow[b4i+6];

        // 4 new conv1 positions: c1[4pp+2 .. 4pp+5]
        float n0[8], n1[8], n2[8], n3[8];
#pragma unroll
        for (int ic = 0; ic < 8; ++ic) {
            float wa = wl[CW1_+ic*2], wb = wl[CW1_+ic*2+1], bb = wl[CB1_+ic];
            n0[ic] = ftanh(bb + wa*e2 + wb*e3);
            n1[ic] = ftanh(bb + wa*e3 + wb*e4);
            n2[ic] = ftanh(bb + wa*e4 + wb*e5);
            n3[ic] = ftanh(bb + wa*e5 + wb*e6);
        }

        // o2[2pp] from (cA,cB,n0,n1); o2[2pp+1] from (n0..n3)
        float oA[8], oB[8];
#pragma unroll
        for (int oc = 0; oc < 8; ++oc) {
            float accA = wl[CB2_+oc], accB = accA;
#pragma unroll
            for (int ic = 0; ic < 8; ++ic) {
                float w0 = wl[CW2_ + oc*32 + ic*4 + 0];
                float w1v= wl[CW2_ + oc*32 + ic*4 + 1];
                float w2v= wl[CW2_ + oc*32 + ic*4 + 2];
                float w3v= wl[CW2_ + oc*32 + ic*4 + 3];
                accA += w0*cA[ic] + w1v*cB[ic] + w2v*n0[ic] + w3v*n1[ic];
                accB += w0*n0[ic] + w1v*n1[ic] + w2v*n2[ic] + w3v*n3[ic];
            }
            oA[oc] = ftanh(accA);
            oB[oc] = ftanh(accB);
        }

        // conv3: q0 = o3[2pp-1] (pp>0), q1 = o3[2pp]
        float q0[8], q1[8];
        if (pp > 0) {
#pragma unroll
            for (int oc = 0; oc < 8; ++oc) {
                float acc = wl[CB3_+oc];
#pragma unroll
                for (int ic = 0; ic < 8; ++ic)
                    acc += wl[CW3_+oc*16+ic*2]*o2p[ic] + wl[CW3_+oc*16+ic*2+1]*oA[ic];
                q0[oc] = ftanh(acc);
            }
        }
#pragma unroll
        for (int oc = 0; oc < 8; ++oc) {
            float acc = wl[CB3_+oc];
#pragma unroll
            for (int ic = 0; ic < 8; ++ic)
                acc += wl[CW3_+oc*16+ic*2]*oA[ic] + wl[CW3_+oc*16+ic*2+1]*oB[ic];
            q1[oc] = ftanh(acc);
        }

        // conv4 r=2pp-2 and r=2pp-1 (pp>0), folded into t3 immediately
        if (pp > 0) {
            const int r0 = 2*pp - 2;
#pragma unroll
            for (int oc = 0; oc < 8; ++oc) {
                float acc = wl[CB4_+oc];
#pragma unroll
                for (int ic = 0; ic < 8; ++ic)
                    acc += wl[CW4_+oc*16+ic*2]*o3p[ic] + wl[CW4_+oc*16+ic*2+1]*q0[ic];
                float fv = ftanh(acc);
                const int wr = W3_ + (oc*4 + r0)*32;
#pragma unroll
                for (int j = 0; j < 32; ++j) t3[j] += fv * wl[wr + j];
            }
#pragma unroll
            for (int oc = 0; oc < 8; ++oc) {
                float acc = wl[CB4_+oc];
#pragma unroll
                for (int ic = 0; ic < 8; ++ic)
                    acc += wl[CW4_+oc*16+ic*2]*q0[ic] + wl[CW4_+oc*16+ic*2+1]*q1[ic];
                float fv = ftanh(acc);
                const int wr = W3_ + (oc*4 + r0 + 1)*32;
#pragma unroll
                for (int j = 0; j < 32; ++j) t3[j] += fv * wl[wr + j];
            }
        }

        // carries
#pragma unroll
        for (int ic = 0; ic < 8; ++ic) {
            cA[ic] = n2[ic]; cB[ic] = n3[ic];
            o2p[ic] = oB[ic]; o3p[ic] = q1[ic];
        }
    }

#pragma unroll
    for (int j = 0; j < 32; ++j) t3[j] = ftanh(t3[j]);

    // dense w4 (32,16) -> pre-norm code g
    float g[16];
#pragma unroll
    for (int j = 0; j < 16; ++j) g[j] = wl[B4_ + j];
#pragma unroll
    for (int i = 0; i < 32; ++i) {
        float fv = t3[i];
#pragma unroll
        for (int j = 0; j < 16; ++j) g[j] += fv * wl[W4_ + i*16 + j];
    }

    {
        float4* gp = (float4*)(g_out + (size_t)row * 16);
        gp[0] = make_float4(g[0],g[1],g[2],g[3]);
        gp[1] = make_float4(g[4],g[5],g[6],g[7]);
        gp[2] = make_float4(g[8],g[9],g[10],g[11]);
        gp[3] = make_float4(g[12],g[13],g[14],g[15]);
    }

    // ---- column sums/sumsq via LDS transpose ----
    __syncthreads();
#pragma unroll
    for (int c = 0; c < 16; ++c) h2s[tid][c] = g[c];
    __syncthreads();
    if (tid < 64) {
        const int c = tid & 15, q = tid >> 4;   // 4 quarters x 16 cols
        float s = 0.0f, ss = 0.0f;
        const int r0 = q * 64;
        for (int r_ = 0; r_ < 64; ++r_) {
            float val = h2s[r0 + r_][c];
            s += val;
            ss += val * val;
        }
        s  += __shfl_xor(s, 16);  s  += __shfl_xor(s, 32);
        ss += __shfl_xor(ss, 16); ss += __shfl_xor(ss, 32);
        if (q == 0) {
            partials[blockIdx.x * 32 + c]      = s;
            partials[blockIdx.x * 32 + 16 + c] = ss;
        }
    }
}

__global__ __attribute__((amdgpu_flat_work_group_size(1024,1024)))
void stat_kernel(const float* __restrict__ partials,
                 float* __restrict__ muinv, int nblocks)
{
    __shared__ float lds[32][33];
    const int t = threadIdx.x;
    const int c = t & 31, chunk = t >> 5;   // 32 chunks x 32 cols
    float s0 = 0.0f, s1 = 0.0f, s2 = 0.0f, s3 = 0.0f;
    for (int k = 0; k < 64; k += 4) {
        s0 += partials[(chunk + (k    )*32)*32 + c];
        s1 += partials[(chunk + (k + 1)*32)*32 + c];
        s2 += partials[(chunk + (k + 2)*32)*32 + c];
        s3 += partials[(chunk + (k + 3)*32)*32 + c];
    }
    lds[chunk][c] = (s0 + s1) + (s2 + s3);
    __syncthreads();
    if (t < 32) {
        float tot = 0.0f;
#pragma unroll
        for (int k = 0; k < 32; ++k) tot += lds[k][t];
        lds[0][t] = tot;
    }
    __syncthreads();
    if (t < 16) {
        float mu  = lds[0][t] * (1.0f / (float)BATCH);
        float var = lds[0][16 + t] * (1.0f / (float)BATCH) - mu * mu;
        muinv[t]      = mu;
        muinv[16 + t] = rsqrtf(var + 1e-5f);
    }
}

// dec LDS weight layout (floats)
#define DW1_  0
#define DB1_  512
#define DW2_  544
#define DB2_  1056
#define MU_   1072
#define NDL   1104

__global__ __attribute__((amdgpu_flat_work_group_size(256,256), amdgpu_waves_per_eu(2,8)))
void dec_kernel(
    const float* __restrict__ g_in,
    const float* __restrict__ noise,
    const float* __restrict__ fading,
    const float* __restrict__ muinv,
    const float* __restrict__ dw1, const float* __restrict__ db1,
    const float* __restrict__ dw2, const float* __restrict__ db2,
    float* __restrict__ out)
{
    __shared__ __align__(16) float wl[NDL];

    const int tid = threadIdx.x;
    const int row = blockIdx.x * 256 + tid;

    wl[DW1_        + tid] = dw1[tid];
    wl[DW1_ + 256  + tid] = dw1[256 + tid];
    wl[DW2_        + tid] = dw2[tid];
    wl[DW2_ + 256  + tid] = dw2[256 + tid];
    if (tid < 32) { wl[DB1_ + tid] = db1[tid]; wl[MU_ + tid] = muinv[tid]; }
    if (tid < 16) { wl[DB2_ + tid] = db2[tid]; }

    float gr[16];
    {
        const float4* gp = (const float4*)(g_in + (size_t)row * 16);
        float4 a0 = gp[0], a1 = gp[1], a2 = gp[2], a3 = gp[3];
        gr[0]=a0.x; gr[1]=a0.y; gr[2]=a0.z; gr[3]=a0.w;
        gr[4]=a1.x; gr[5]=a1.y; gr[6]=a1.z; gr[7]=a1.w;
        gr[8]=a2.x; gr[9]=a2.y; gr[10]=a2.z; gr[11]=a2.w;
        gr[12]=a3.x; gr[13]=a3.y; gr[14]=a3.z; gr[15]=a3.w;
    }

    float hr[3], hi[3];
    {
        const float2* fd = (const float2*)(fading + (size_t)row * 6);
        float2 f0 = fd[0], f1 = fd[1], f2 = fd[2];
        hr[0] = f0.x * INV_SQRT2; hi[0] = f0.y * INV_SQRT2;
        hr[1] = f1.x * INV_SQRT2; hi[1] = f1.y * INV_SQRT2;
        hr[2] = f2.x * INV_SQRT2; hi[2] = f2.y * INV_SQRT2;
    }

    __syncthreads();   // weights + muinv visible

    float enc[16];
#pragma unroll
    for (int c = 0; c < 16; ++c)
        enc[c] = (gr[c] - wl[MU_ + c]) * wl[MU_ + 16 + c];

    // causal 3-tap complex conv + noise
    float cvec[16];
    {
        const float4* npz = (const float4*)(noise + (size_t)row * 16);
        float4 n0 = npz[0], n1 = npz[1], n2 = npz[2], n3 = npz[3];
        float nz[16] = {n0.x,n0.y,n0.z,n0.w, n1.x,n1.y,n1.z,n1.w,
                        n2.x,n2.y,n2.z,n2.w, n3.x,n3.y,n3.z,n3.w};
#pragma unroll
        for (int n = 0; n < 8; ++n) {
            float sr = 0.0f, si = 0.0f;
#pragma unroll
            for (int t = 0; t < 3; ++t) {
                if (n - t >= 0) {
                    float xr = enc[2*(n-t)], xi = enc[2*(n-t)+1];
                    sr += hr[t]*xr - hi[t]*xi;
                    si += hr[t]*xi + hi[t]*xr;
                }
            }
            cvec[2*n]   = sr + nz[2*n]   * NOISE_STD;
            cvec[2*n+1] = si + nz[2*n+1] * NOISE_STD;
        }
    }

    // decoder dense1 (16->32) + ELU
    float d[32];
#pragma unroll
    for (int j = 0; j < 32; ++j) d[j] = wl[DB1_ + j];
#pragma unroll
    for (int i = 0; i < 16; ++i) {
        float ci = cvec[i];
#pragma unroll
        for (int j = 0; j < 32; ++j) d[j] += ci * wl[DW1_ + i*32 + j];
    }
#pragma unroll
    for (int j = 0; j < 32; ++j) d[j] = eluf(d[j]);

    // decoder dense2 (32->16)
    float o[16];
#pragma unroll
    for (int j = 0; j < 16; ++j) o[j] = wl[DB2_ + j];
#pragma unroll
    for (int i = 0; i < 32; ++i) {
        float di = d[i];
#pragma unroll
        for (int j = 0; j < 16; ++j) o[j] += di * wl[DW2_ + i*16 + j];
    }

    float4* op = (float4*)(out + (size_t)row * 16);
    op[0] = make_float4(o[0],o[1],o[2],o[3]);
    op[1] = make_float4(o[4],o[5],o[6],o[7]);
    op[2] = make_float4(o[8],o[9],o[10],o[11]);
    op[3] = make_float4(o[12],o[13],o[14],o[15]);
}

extern "C" void kernel_launch(void* const* d_in, const int* in_sizes, int n_in,
                              void* d_out, int out_size, void* d_ws, size_t ws_size,
                              hipStream_t stream) {
    (void)in_sizes; (void)n_in; (void)out_size; (void)ws_size;

    const float* x      = (const float*)d_in[0];
    const float* noise  = (const float*)d_in[1];
    const float* fading = (const float*)d_in[2];
    const float* w1  = (const float*)d_in[3];
    const float* b1  = (const float*)d_in[4];
    const float* w2  = (const float*)d_in[5];
    const float* b2  = (const float*)d_in[6];
    const float* cw1 = (const float*)d_in[7];
    const float* cb1 = (const float*)d_in[8];
    const float* cw2 = (const float*)d_in[9];
    const float* cb2 = (const float*)d_in[10];
    const float* cw3 = (const float*)d_in[11];
    const float* cb3 = (const float*)d_in[12];
    const float* cw4 = (const float*)d_in[13];
    const float* cb4 = (const float*)d_in[14];
    const float* w3  = (const float*)d_in[15];
    const float* b3  = (const float*)d_in[16];
    const float* w4  = (const float*)d_in[17];
    const float* b4  = (const float*)d_in[18];
    const float* dw1 = (const float*)d_in[19];
    const float* db1 = (const float*)d_in[20];
    const float* dw2 = (const float*)d_in[21];
    const float* db2 = (const float*)d_in[22];
    float* outp = (float*)d_out;

    float* ws       = (float*)d_ws;
    float* muinv    = ws;                 // 32 floats
    float* partials = ws + 32;            // 2048*32 floats
    float* g        = ws + 32 + 2048*32;  // BATCH*16 floats

    const int nb = BATCH / 256;  // 2048

    enc_kernel<<<nb, 256, 0, stream>>>(x, w1,b1, w2,b2, cw1,cb1, cw2,cb2,
                                       cw3,cb3, cw4,cb4, w3,b3, w4,b4,
                                       g, partials);
    stat_kernel<<<1, 1024, 0, stream>>>(partials, muinv, nb);
    dec_kernel<<<nb, 256, 0, stream>>>(g, noise, fading, muinv,
                                       dw1,db1, dw2,db2, outp);
}